// Round 4
// baseline (1282.172 us; speedup 1.0000x reference)
//
#include <hip/hip_runtime.h>

typedef __bf16 bf16_t;
typedef bf16_t bf16x8 __attribute__((ext_vector_type(8)));
typedef float  floatx4 __attribute__((ext_vector_type(4)));
typedef unsigned short u16;
typedef unsigned int   u32;
typedef unsigned long long u64;

#define DEV __device__ __forceinline__

static constexpr int B_  = 256;
static constexpr int T_  = 64;
static constexpr int H_  = 512;
static constexpr int G_  = 2048;   // 4*H
static constexpr int INS = 500;
static constexpr int NDP = 16640;  // padded OUT_DIM
static constexpr int NDR = 16532;  // real OUT_DIM

DEV u16 f2bf(float f) {
  unsigned u = __builtin_bit_cast(unsigned, f);
  u += 0x7FFFu + ((u >> 16) & 1u);
  return (u16)(u >> 16);
}
DEV float bf2f(u16 h) {
  unsigned u = ((unsigned)h) << 16;
  return __builtin_bit_cast(float, u);
}
DEV float sigm(float x)  { return 1.f / (1.f + __expf(-x)); }
DEV float tanh_(float x) { return 1.f - 2.f / (__expf(2.f * x) + 1.f); }

DEV void gload16(const u16* g, u16* l) {
  __builtin_amdgcn_global_load_lds(
      (const __attribute__((address_space(1))) void*)g,
      (__attribute__((address_space(3))) void*)l, 16, 0, 0);
}

// ---------------------------------------------------------------- prep kernels
__global__ void prep_weights_kernel(
    const float* __restrict__ w_ih0, const float* __restrict__ w_hh0,
    const float* __restrict__ b_ih0, const float* __restrict__ b_hh0,
    const float* __restrict__ w_ih1, const float* __restrict__ w_hh1,
    const float* __restrict__ b_ih1, const float* __restrict__ b_hh1,
    const float* __restrict__ fc_w,  const float* __restrict__ fc_b,
    u16* __restrict__ wih0b, u16* __restrict__ whh0b,
    u16* __restrict__ w1b,   u16* __restrict__ fcwb,
    float* __restrict__ bias0p, float* __restrict__ bias1p,
    float* __restrict__ fcbp)
{
  const int gsz = gridDim.x * blockDim.x;
  const int g0  = blockIdx.x * blockDim.x + threadIdx.x;
  // permuted gate order: p = (j>>4)*64 + (j&15)*4 + g  (j = hidden, g = i/f/g/o)
  for (int i = g0; i < 2048 * 512; i += gsz) {
    int pp = i >> 9, k = i & 511;
    int s = pp >> 6, rr = pp & 63, jj = rr >> 2, g = rr & 3;
    int srow = g * 512 + s * 16 + jj;
    wih0b[i] = f2bf(k < INS ? w_ih0[(size_t)srow * INS + k] : 0.f);
    whh0b[i] = f2bf(w_hh0[(size_t)srow * 512 + k]);
  }
  for (int i = g0; i < 2048 * 1024; i += gsz) {
    int pp = i >> 10, k = i & 1023;
    int s = pp >> 6, rr = pp & 63, jj = rr >> 2, g = rr & 3;
    int srow = g * 512 + s * 16 + jj;
    float v = (k < 512) ? w_ih1[(size_t)srow * 512 + k]
                        : w_hh1[(size_t)srow * 512 + (k - 512)];
    w1b[i] = f2bf(v);
  }
  for (int i = g0; i < NDP * 512; i += gsz) {
    int n = i >> 9, k = i & 511;
    fcwb[i] = f2bf(n < NDR ? fc_w[(size_t)n * 512 + k] : 0.f);
  }
  for (int i = g0; i < 2048; i += gsz) {
    int s = i >> 6, rr = i & 63, jj = rr >> 2, g = rr & 3;
    int srow = g * 512 + s * 16 + jj;
    bias0p[i] = b_ih0[srow] + b_hh0[srow];
    bias1p[i] = b_ih1[srow] + b_hh1[srow];
  }
  for (int i = g0; i < NDP; i += gsz) fcbp[i] = (i < NDR) ? fc_b[i] : 0.f;
}

__global__ void prep_x_kernel(const float* __restrict__ x, u16* __restrict__ xb,
                              u32* __restrict__ hp1u) {
  const int gsz = gridDim.x * blockDim.x;
  for (int i = blockIdx.x * blockDim.x + threadIdx.x; i < T_ * B_ * 512; i += gsz) {
    int k = i & 511;
    int b = (i >> 9) & 255;
    int t = i >> 17;
    float v = (k < INS) ? x[((size_t)b * T_ + t) * INS + k] : 0.f;
    xb[i] = f2bf(v);
  }
  // hp1 slot 1 = h1(-1) = 0 with tag 1 (consumed at round t=1)
  for (int i = blockIdx.x * blockDim.x + threadIdx.x; i < B_ * H_; i += gsz)
    hp1u[B_ * H_ + i] = 1u;
}

__global__ void prep_sigma_kernel(const float* __restrict__ raw,
                                  u16* __restrict__ Gb, u16* __restrict__ Ldb,
                                  float* __restrict__ idio)
{
  const int gsz = gridDim.x * blockDim.x;
  const int g0  = blockIdx.x * blockDim.x + threadIdx.x;
  for (int i = g0; i < 256 * 512 * 32; i += gsz) {
    int b = i >> 14, rr = i & 16383, n = rr >> 5, f = rr & 31;
    const float* rb = raw + (size_t)b * NDP;
    float ld = (n < 500) ? rb[n * 32 + f] : 0.f;
    float fv = __expf(rb[16000 + f]);
    Ldb[i] = f2bf(ld);
    Gb[i]  = f2bf(ld * fv);
  }
  for (int i = g0; i < 256 * 512; i += gsz) {
    int b = i >> 9, a = i & 511;
    if (a < 500) idio[(size_t)b * 500 + a] = __expf(raw[(size_t)b * NDP + 16032 + a]);
  }
}

// ---------------------------------------------------------------- GEMM: C[M][N] = A[M][K] @ Bw[N][K]^T + bias
// global_load_lds width-16 staging (m97 structure): linear LDS dest, inverse-swizzled
// global source, swizzled ds_read (both-sides rule).
template <int OUT_BF16>
__global__ __launch_bounds__(256) void gemm_bt(
    const u16* __restrict__ A, const u16* __restrict__ Bw,
    const float* __restrict__ bias, void* __restrict__ C,
    int M, int N, int K)
{
  __shared__ alignas(16) u16 As[128 * 32];
  __shared__ alignas(16) u16 Bs[128 * 32];
  const int tid = threadIdx.x;
  const int wave = tid >> 6, lane = tid & 63;
  const int m0 = blockIdx.y * 128, n0 = blockIdx.x * 128;
  const int wr = wave >> 1, wc = wave & 1;

  // staging map: 16B slot s in [0,512): content (row = s>>2, ks = (s&3)^(row&3))
  const int sl0 = wave * 64 + lane;
  const int sl1 = 256 + wave * 64 + lane;
  const int r0s = sl0 >> 2, k0s = (sl0 & 3) ^ (r0s & 3);
  const int r1s = sl1 >> 2, k1s = (sl1 & 3) ^ (r1s & 3);
  const u16* srcA0 = A  + (size_t)(m0 + r0s) * K + k0s * 8;
  const u16* srcA1 = A  + (size_t)(m0 + r1s) * K + k1s * 8;
  const u16* srcB0 = Bw + (size_t)(n0 + r0s) * K + k0s * 8;
  const u16* srcB1 = Bw + (size_t)(n0 + r1s) * K + k1s * 8;
  u16* ldsA0 = As + (size_t)(wave * 64) * 8;
  u16* ldsA1 = As + (size_t)(256 + wave * 64) * 8;
  u16* ldsB0 = Bs + (size_t)(wave * 64) * 8;
  u16* ldsB1 = Bs + (size_t)(256 + wave * 64) * 8;

  floatx4 zero = {0.f, 0.f, 0.f, 0.f};
  floatx4 acc[4][4];
#pragma unroll
  for (int i = 0; i < 4; i++)
#pragma unroll
    for (int j = 0; j < 4; j++) acc[i][j] = zero;

  for (int kc = 0; kc < K; kc += 32) {
    __syncthreads();                 // previous tile's reads done
    gload16(srcA0 + kc, ldsA0);
    gload16(srcA1 + kc, ldsA1);
    gload16(srcB0 + kc, ldsB0);
    gload16(srcB1 + kc, ldsB1);
    __syncthreads();                 // vmcnt(0) drain -> LDS-DMA complete

    const int kg = lane >> 4;
    bf16x8 af[4], bfr[4];
#pragma unroll
    for (int i = 0; i < 4; i++) {
      int rowa = wr * 64 + i * 16 + (lane & 15);
      af[i] = *(const bf16x8*)(As + rowa * 32 + ((kg ^ (rowa & 3)) << 3));
      int rowb = wc * 64 + i * 16 + (lane & 15);
      bfr[i] = *(const bf16x8*)(Bs + rowb * 32 + ((kg ^ (rowb & 3)) << 3));
    }
#pragma unroll
    for (int i = 0; i < 4; i++)
#pragma unroll
      for (int j = 0; j < 4; j++)
        acc[i][j] = __builtin_amdgcn_mfma_f32_16x16x32_bf16(af[i], bfr[j], acc[i][j], 0, 0, 0);
  }

  const int r0 = (lane >> 4) * 4, cl = lane & 15;
#pragma unroll
  for (int j = 0; j < 4; j++) {
    int col = n0 + wc * 64 + j * 16 + cl;
    float bv = bias[col];
#pragma unroll
    for (int i = 0; i < 4; i++) {
      int row = m0 + wr * 64 + i * 16 + r0;
#pragma unroll
      for (int r = 0; r < 4; r++) {
        float v = acc[i][j][r] + bv;
        if (OUT_BF16) ((u16*)C)[(size_t)(row + r) * N + col] = f2bf(v);
        else          ((float*)C)[(size_t)(row + r) * N + col] = v;
      }
    }
  }
}

// ---------------------------------------------------------------- Fused 2-layer LSTM, tagged-word exchange
// 256 blocks x 512 threads (1/CU, all co-resident). bm=blockIdx>>5 (8 batch groups
// of 32), bn=blockIdx&31 (32 gate slices of 64 rows). 8 waves = 4 row-groups x 2
// K-halves. h exchange: u32 = (bf16 h)<<16 | round_tag. Consumers poll the DATA
// WORDS directly (each word self-validating; u64-load tearing harmless since each
// 32b word validates independently) -> one memory round-trip per step. No flags,
// no producer-side drains. Depth-2 ping-pong overwrite safety: a block writes
// round t only after observing all peers' round t-1 tags; a peer's tag-(t) store
// is issued after syncthreads(1), i.e. after ALL its threads' round-(t-1) loads
// of the to-be-overwritten slot returned data.
__global__ __launch_bounds__(512, 2) void lstm_fused_kernel(
    const u16* __restrict__ xg,     // [64][256][2048] bf16, permuted gate order
    const u16* __restrict__ whh0,   // [2048][512]  bf16, permuted rows
    const u16* __restrict__ w1,     // [2048][1024] bf16, permuted rows, cols [w_ih1 | w_hh1]
    const float* __restrict__ bias1p,
    u32* __restrict__ hp0,          // [2][256][512] tagged h0 ping-pong
    u32* __restrict__ hp1,          // [2][256][512] tagged h1 ping-pong
    u16* __restrict__ hfin)         // [256][512] final h1(63), plain bf16
{
  const int tid  = threadIdx.x;
  const int wv   = tid >> 6, lane = tid & 63;
  const int rw   = wv >> 1,  kh   = wv & 1;
  const int bl   = lane & 15, qd  = lane >> 4;
  const int bm   = blockIdx.x >> 5;
  const int bn   = blockIdx.x & 31;
  const int bbase = bm << 5;        // 32 batches
  const int pbase = bn << 6;        // 64 gate rows

  __shared__ alignas(16) u16 h_lds[2 * 32 * 512];     // 64 KB: [0]=h0(t-1), [1]=h1(t-2)
  __shared__ alignas(16) float gates[2 * 4 * 32 * 68]; // double-buffered partial gates

  bf16x8 wf0[8], wf1[16];
  {
    const u16* wp = whh0 + (size_t)(pbase + rw * 16 + bl) * 512 + kh * 256 + qd * 8;
#pragma unroll
    for (int kc = 0; kc < 8; kc++)  wf0[kc] = *(const bf16x8*)(wp + kc * 32);
    const u16* wq = w1 + (size_t)(pbase + rw * 16 + bl) * 1024 + kh * 512 + qd * 8;
#pragma unroll
    for (int kc = 0; kc < 16; kc++) wf1[kc] = *(const bf16x8*)(wq + kc * 32);
  }

  const int eb = tid >> 4, ej = tid & 15;          // elementwise ownership
  const float4 bq = *(const float4*)(bias1p + pbase + ej * 4);
  float c0 = 0.f, c1 = 0.f;
  const size_t hoff = (size_t)(bbase + eb) * H_ + (bn << 4) + ej;
  const floatx4 zero = {0.f, 0.f, 0.f, 0.f};

#pragma unroll 1
  for (int t = 0; t <= 64; t++) {
    const unsigned exp_ = (unsigned)t;
    // xg prefetch first: latency hides under the poll
    ushort4 xr = {0, 0, 0, 0};
    if (t < 64)
      xr = *(const ushort4*)(xg + ((size_t)t * B_ + bbase + eb) * G_ + pbase + ej * 4);

    // ---- Phase A: issue ALL loads (both halves) up front, poll jointly -> 1 RT
    {
      const u64* sp0 = (const u64*)(hp0 + (size_t)((t + 1) & 1) * (B_ * H_));
      const u64* sp1 = (const u64*)(hp1 + (size_t)(t & 1) * (B_ * H_));
      u64 v[8][4];
      bool okd[8];
#pragma unroll
      for (int g = 0; g < 8; g++) {
        const u64* s = (g < 4) ? sp0 : sp1;
        int idx = tid + ((g & 3) << 9), bb = idx >> 6, u = idx & 63;
        const u64* pp = s + (size_t)(bbase + bb) * 256 + (size_t)u * 4;
#pragma unroll
        for (int j = 0; j < 4; j++)
          v[g][j] = __hip_atomic_load(pp + j, __ATOMIC_RELAXED, __HIP_MEMORY_SCOPE_AGENT);
      }
#pragma unroll
      for (int g = 0; g < 8; g++) {
        unsigned x = 0;
#pragma unroll
        for (int j = 0; j < 4; j++) {
          x |= (unsigned)v[g][j] ^ exp_;
          x |= (unsigned)(v[g][j] >> 32) ^ exp_;
        }
        okd[g] = ((x & 0xFFFFu) == 0);
      }
      bool allok = okd[0] && okd[1] && okd[2] && okd[3] &&
                   okd[4] && okd[5] && okd[6] && okd[7];
      while (!__all(allok)) {
        __builtin_amdgcn_s_sleep(2);
#pragma unroll
        for (int g = 0; g < 8; g++) {
          if (!okd[g]) {
            const u64* s = (g < 4) ? sp0 : sp1;
            int idx = tid + ((g & 3) << 9), bb = idx >> 6, u = idx & 63;
            const u64* pp = s + (size_t)(bbase + bb) * 256 + (size_t)u * 4;
            unsigned x = 0;
#pragma unroll
            for (int j = 0; j < 4; j++) {
              v[g][j] = __hip_atomic_load(pp + j, __ATOMIC_RELAXED, __HIP_MEMORY_SCOPE_AGENT);
              x |= (unsigned)v[g][j] ^ exp_;
              x |= (unsigned)(v[g][j] >> 32) ^ exp_;
            }
            okd[g] = ((x & 0xFFFFu) == 0);
          }
        }
        allok = okd[0] && okd[1] && okd[2] && okd[3] &&
                okd[4] && okd[5] && okd[6] && okd[7];
      }
      // scatter to LDS (b128, swizzled rows, conflict-free)
#pragma unroll
      for (int g = 0; g < 8; g++) {
        int idx = tid + ((g & 3) << 9), bb = idx >> 6, u = idx & 63;
        int dst = (g < 4 ? 0 : 16384) + bb * 512 + ((u ^ (bb & 7)) << 3);
        uint4 q;
        q.x = ((unsigned)(v[g][0] >> 16) & 0xFFFFu) | ((unsigned)(v[g][0] >> 32) & 0xFFFF0000u);
        q.y = ((unsigned)(v[g][1] >> 16) & 0xFFFFu) | ((unsigned)(v[g][1] >> 32) & 0xFFFF0000u);
        q.z = ((unsigned)(v[g][2] >> 16) & 0xFFFFu) | ((unsigned)(v[g][2] >> 32) & 0xFFFF0000u);
        q.w = ((unsigned)(v[g][3] >> 16) & 0xFFFFu) | ((unsigned)(v[g][3] >> 32) & 0xFFFF0000u);
        *(uint4*)(h_lds + dst) = q;
      }
    }
    __syncthreads();                               // (1) h_lds ready

    // ---- Phase B: MFMAs (partial K per wave)
    floatx4 acc0[2] = {zero, zero};
    floatx4 acc1[2] = {zero, zero};
    if (t < 64) {
#pragma unroll
      for (int kc = 0; kc < 8; kc++) {             // L0: this wave's K-half of h0
        int kg = kh * 32 + kc * 4 + qd;
        int sw = (kg ^ (bl & 7)) << 3;
        bf16x8 a0 = *(const bf16x8*)(h_lds + bl * 512 + sw);
        bf16x8 a1 = *(const bf16x8*)(h_lds + (16 + bl) * 512 + sw);
        acc0[0] = __builtin_amdgcn_mfma_f32_16x16x32_bf16(a0, wf0[kc], acc0[0], 0, 0, 0);
        acc0[1] = __builtin_amdgcn_mfma_f32_16x16x32_bf16(a1, wf0[kc], acc0[1], 0, 0, 0);
      }
    }
    {
      const u16* hb = h_lds + (kh ? 16384 : 0);    // L1 operand: kh=0 -> h0, kh=1 -> h1
#pragma unroll
      for (int kc = 0; kc < 16; kc++) {
        int kg = kc * 4 + qd;
        int sw = (kg ^ (bl & 7)) << 3;
        bf16x8 a0 = *(const bf16x8*)(hb + bl * 512 + sw);
        bf16x8 a1 = *(const bf16x8*)(hb + (16 + bl) * 512 + sw);
        acc1[0] = __builtin_amdgcn_mfma_f32_16x16x32_bf16(a0, wf1[kc], acc1[0], 0, 0, 0);
        acc1[1] = __builtin_amdgcn_mfma_f32_16x16x32_bf16(a1, wf1[kc], acc1[1], 0, 0, 0);
      }
    }

    // ---- Phase C: partial gate tiles -> double-buffered gates
    float* gb_ = gates + (t & 1) * (4 * 32 * 68);
    {
      const int rowc = rw * 16 + bl;
#pragma unroll
      for (int bt = 0; bt < 2; bt++)
#pragma unroll
        for (int r = 0; r < 4; r++) {
          int bat = bt * 16 + qd * 4 + r;
          gb_[((kh * 2 + 0) * 32 + bat) * 68 + rowc] = acc0[bt][r];
          gb_[((kh * 2 + 1) * 32 + bat) * 68 + rowc] = acc1[bt][r];
        }
    }
    __syncthreads();                               // (2) gates ready

    // ---- Phase D: combine K-halves, elementwise, fire-and-forget tagged stores
    if (t < 64) {                                  // layer 0 -> h0(t) -> hp0 slot t&1
      float4 ga = *(const float4*)(gb_ + (0 * 32 + eb) * 68 + ej * 4);
      float4 gc = *(const float4*)(gb_ + (2 * 32 + eb) * 68 + ej * 4);
      float gi = ga.x + gc.x + bf2f(xr.x);
      float gf = ga.y + gc.y + bf2f(xr.y);
      float gg = ga.z + gc.z + bf2f(xr.z);
      float go = ga.w + gc.w + bf2f(xr.w);
      c0 = sigm(gf) * c0 + sigm(gi) * tanh_(gg);
      float h = sigm(go) * tanh_(c0);
      __hip_atomic_store(hp0 + (size_t)(t & 1) * (B_ * H_) + hoff,
                         ((unsigned)f2bf(h) << 16) | (unsigned)(t + 1),
                         __ATOMIC_RELAXED, __HIP_MEMORY_SCOPE_AGENT);
    }
    if (t >= 1) {                                  // layer 1 -> h1(t-1)
      float4 ga = *(const float4*)(gb_ + (1 * 32 + eb) * 68 + ej * 4);
      float4 gc = *(const float4*)(gb_ + (3 * 32 + eb) * 68 + ej * 4);
      float gi = ga.x + gc.x + bq.x;
      float gf = ga.y + gc.y + bq.y;
      float gg = ga.z + gc.z + bq.z;
      float go = ga.w + gc.w + bq.w;
      c1 = sigm(gf) * c1 + sigm(gi) * tanh_(gg);
      float h = sigm(go) * tanh_(c1);
      u16 hb = f2bf(h);
      if (t < 64)
        __hip_atomic_store(hp1 + (size_t)((t + 1) & 1) * (B_ * H_) + hoff,
                           ((unsigned)hb << 16) | (unsigned)(t + 1),
                           __ATOMIC_RELAXED, __HIP_MEMORY_SCOPE_AGENT);
      else
        hfin[hoff] = hb;                           // final h1(63), kernel-boundary coherent
    }
    // no trailing barrier: next round's poll is the synchronization
  }
}

// ---------------------------------------------------------------- Sigma: out[b] = G_b @ Ld_b^T + diag(idio)
__global__ __launch_bounds__(256) void sigma_kernel(
    const u16* __restrict__ Gb, const u16* __restrict__ Ldb,
    const float* __restrict__ idio, float* __restrict__ out)
{
  const int bz = blockIdx.z;
  const int n0 = blockIdx.y * 128;
  const int m0 = blockIdx.x * 128;
  __shared__ alignas(16) u16 As[128 * 32];
  __shared__ alignas(16) u16 Bs[128 * 32];
  const int tid = threadIdx.x, wave = tid >> 6, lane = tid & 63;
  const int wr = wave >> 1, wc = wave & 1;

  const u16* ga = Gb  + (size_t)bz * (512 * 32) + n0 * 32;
  const u16* gb = Ldb + (size_t)bz * (512 * 32) + m0 * 32;
#pragma unroll
  for (int i = 0; i < 2; i++) {
    int idx = tid + (i << 8);
    int row = idx >> 2, ks = idx & 3;
    int off = row * 32 + ((ks ^ (row & 3)) << 3);
    *(uint4*)(As + off) = *(const uint4*)(ga + idx * 8);
    *(uint4*)(Bs + off) = *(const uint4*)(gb + idx * 8);
  }
  __syncthreads();

  const int kg = lane >> 4;
  bf16x8 af[4], bfr[4];
#pragma unroll
  for (int i = 0; i < 4; i++) {
    int rowa = wr * 64 + i * 16 + (lane & 15);
    af[i] = *(const bf16x8*)(As + rowa * 32 + ((kg ^ (rowa & 3)) << 3));
    int rowb = wc * 64 + i * 16 + (lane & 15);
    bfr[i] = *(const bf16x8*)(Bs + rowb * 32 + ((kg ^ (rowb & 3)) << 3));
  }
  floatx4 zero = {0.f, 0.f, 0.f, 0.f};
  floatx4 acc[4][4];
#pragma unroll
  for (int i = 0; i < 4; i++)
#pragma unroll
    for (int j = 0; j < 4; j++)
      acc[i][j] = __builtin_amdgcn_mfma_f32_16x16x32_bf16(af[i], bfr[j], zero, 0, 0, 0);

  const int r0 = (lane >> 4) * 4, cl = lane & 15;
  float* ob = out + (size_t)bz * 250000;
#pragma unroll
  for (int j = 0; j < 4; j++) {
    int col = m0 + wc * 64 + j * 16 + cl;
#pragma unroll
    for (int i = 0; i < 4; i++) {
      int row = n0 + wr * 64 + i * 16 + r0;
#pragma unroll
      for (int r = 0; r < 4; r++) {
        int rr = row + r;
        if (rr < 500 && col < 500) {
          float v = acc[i][j][r];
          if (rr == col) v += idio[(size_t)bz * 500 + rr];
          ob[(size_t)rr * 500 + col] = v;
        }
      }
    }
  }
}

// ---------------------------------------------------------------- launcher
extern "C" void kernel_launch(void* const* d_in, const int* in_sizes, int n_in,
                              void* d_out, int out_size, void* d_ws, size_t ws_size,
                              hipStream_t stream)
{
  const float* x     = (const float*)d_in[0];
  const float* w_ih0 = (const float*)d_in[1];
  const float* w_hh0 = (const float*)d_in[2];
  const float* b_ih0 = (const float*)d_in[3];
  const float* b_hh0 = (const float*)d_in[4];
  const float* w_ih1 = (const float*)d_in[5];
  const float* w_hh1 = (const float*)d_in[6];
  const float* b_ih1 = (const float*)d_in[7];
  const float* b_hh1 = (const float*)d_in[8];
  const float* fc_w  = (const float*)d_in[9];
  const float* fc_b  = (const float*)d_in[10];
  float* out = (float*)d_out;

  char* p = (char*)d_ws;
  auto alloc = [&](size_t n) { char* r = p; p += (n + 255) & ~(size_t)255; return r; };

  u16*  xb     = (u16*)alloc((size_t)T_ * B_ * 512 * 2);
  u16*  wih0b  = (u16*)alloc((size_t)2048 * 512 * 2);
  u16*  whh0b  = (u16*)alloc((size_t)2048 * 512 * 2);
  u16*  w1b    = (u16*)alloc((size_t)2048 * 1024 * 2);
  u16*  fcwb   = (u16*)alloc((size_t)NDP * 512 * 2);
  float* bias0p = (float*)alloc(2048 * 4);
  float* bias1p = (float*)alloc(2048 * 4);
  float* fcbp   = (float*)alloc((size_t)NDP * 4);
  u16*  xg0    = (u16*)alloc((size_t)T_ * B_ * G_ * 2);
  u32*  hp0    = (u32*)alloc((size_t)2 * B_ * H_ * 4);
  u32*  hp1    = (u32*)alloc((size_t)2 * B_ * H_ * 4);
  u16*  hfin   = (u16*)alloc((size_t)B_ * H_ * 2);
  float* raw    = (float*)alloc((size_t)B_ * NDP * 4);
  u16*  Gbuf   = (u16*)alloc((size_t)256 * 512 * 32 * 2);
  u16*  Ldbuf  = (u16*)alloc((size_t)256 * 512 * 32 * 2);
  float* idio   = (float*)alloc((size_t)256 * 512 * 4);

  // tag 0 everywhere: h0(-1) (hp0 slot 1) and h1(-2) (hp1 slot 0) read at round 0
  hipMemsetAsync(hp0, 0, (size_t)2 * B_ * H_ * 4, stream);
  hipMemsetAsync(hp1, 0, (size_t)2 * B_ * H_ * 4, stream);

  dim3 blk(256);
  prep_weights_kernel<<<512, blk, 0, stream>>>(w_ih0, w_hh0, b_ih0, b_hh0,
                                               w_ih1, w_hh1, b_ih1, b_hh1,
                                               fc_w, fc_b,
                                               wih0b, whh0b, w1b, fcwb,
                                               bias0p, bias1p, fcbp);
  prep_x_kernel<<<1024, blk, 0, stream>>>(x, xb, hp1);

  // xg0 = xb @ wih0b^T + (b_ih0 + b_hh0)   [16384 x 2048 x 512]
  gemm_bt<1><<<dim3(G_ / 128, (T_ * B_) / 128), blk, 0, stream>>>(
      xb, wih0b, bias0p, xg0, T_ * B_, G_, 512);

  // fused two-layer LSTM; final h1(63) lands in hfin
  lstm_fused_kernel<<<256, dim3(512), 0, stream>>>(xg0, whh0b, w1b, bias1p, hp0, hp1, hfin);

  // raw = h1_final @ fcwb^T + fc_b  [256 x 16640 x 512]
  gemm_bt<0><<<dim3(NDP / 128, B_ / 128), blk, 0, stream>>>(
      hfin, fcwb, fcbp, raw, B_, NDP, 512);

  prep_sigma_kernel<<<1024, blk, 0, stream>>>(raw, Gbuf, Ldbuf, idio);
  sigma_kernel<<<dim3(4, 4, 256), blk, 0, stream>>>(Gbuf, Ldbuf, idio, out);
}

// Round 5
// 946.686 us; speedup vs baseline: 1.3544x; 1.3544x over previous
//
#include <hip/hip_runtime.h>

typedef __bf16 bf16_t;
typedef bf16_t bf16x8 __attribute__((ext_vector_type(8)));
typedef float  floatx4 __attribute__((ext_vector_type(4)));
typedef unsigned short u16;
typedef unsigned int   u32;
typedef unsigned long long u64;

#define DEV __device__ __forceinline__

static constexpr int B_  = 256;
static constexpr int T_  = 64;
static constexpr int H_  = 512;
static constexpr int G_  = 2048;   // 4*H
static constexpr int INS = 500;
static constexpr int NDP = 16640;  // padded OUT_DIM
static constexpr int NDR = 16532;  // real OUT_DIM

DEV u16 f2bf(float f) {
  unsigned u = __builtin_bit_cast(unsigned, f);
  u += 0x7FFFu + ((u >> 16) & 1u);
  return (u16)(u >> 16);
}
DEV float bf2f(u16 h) {
  unsigned u = ((unsigned)h) << 16;
  return __builtin_bit_cast(float, u);
}
DEV float sigm(float x)  { return 1.f / (1.f + __expf(-x)); }
DEV float tanh_(float x) { return 1.f - 2.f / (__expf(2.f * x) + 1.f); }

DEV void gload16(const u16* g, u16* l) {
  __builtin_amdgcn_global_load_lds(
      (const __attribute__((address_space(1))) void*)g,
      (__attribute__((address_space(3))) void*)l, 16, 0, 0);
}

// ---------------------------------------------------------------- prep kernels
__global__ void prep_weights_kernel(
    const float* __restrict__ w_ih0, const float* __restrict__ w_hh0,
    const float* __restrict__ b_ih0, const float* __restrict__ b_hh0,
    const float* __restrict__ w_ih1, const float* __restrict__ w_hh1,
    const float* __restrict__ b_ih1, const float* __restrict__ b_hh1,
    const float* __restrict__ fc_w,  const float* __restrict__ fc_b,
    u16* __restrict__ wih0b, u16* __restrict__ whh0b,
    u16* __restrict__ w1b,   u16* __restrict__ fcwb,
    float* __restrict__ bias0p, float* __restrict__ bias1p,
    float* __restrict__ fcbp)
{
  const int gsz = gridDim.x * blockDim.x;
  const int g0  = blockIdx.x * blockDim.x + threadIdx.x;
  // permuted gate order: p = (j>>4)*64 + (j&15)*4 + g  (j = hidden, g = i/f/g/o)
  for (int i = g0; i < 2048 * 512; i += gsz) {
    int pp = i >> 9, k = i & 511;
    int s = pp >> 6, rr = pp & 63, jj = rr >> 2, g = rr & 3;
    int srow = g * 512 + s * 16 + jj;
    wih0b[i] = f2bf(k < INS ? w_ih0[(size_t)srow * INS + k] : 0.f);
    whh0b[i] = f2bf(w_hh0[(size_t)srow * 512 + k]);
  }
  for (int i = g0; i < 2048 * 1024; i += gsz) {
    int pp = i >> 10, k = i & 1023;
    int s = pp >> 6, rr = pp & 63, jj = rr >> 2, g = rr & 3;
    int srow = g * 512 + s * 16 + jj;
    float v = (k < 512) ? w_ih1[(size_t)srow * 512 + k]
                        : w_hh1[(size_t)srow * 512 + (k - 512)];
    w1b[i] = f2bf(v);
  }
  for (int i = g0; i < NDP * 512; i += gsz) {
    int n = i >> 9, k = i & 511;
    fcwb[i] = f2bf(n < NDR ? fc_w[(size_t)n * 512 + k] : 0.f);
  }
  for (int i = g0; i < 2048; i += gsz) {
    int s = i >> 6, rr = i & 63, jj = rr >> 2, g = rr & 3;
    int srow = g * 512 + s * 16 + jj;
    bias0p[i] = b_ih0[srow] + b_hh0[srow];
    bias1p[i] = b_ih1[srow] + b_hh1[srow];
  }
  for (int i = g0; i < NDP; i += gsz) fcbp[i] = (i < NDR) ? fc_b[i] : 0.f;
}

__global__ void prep_x_kernel(const float* __restrict__ x, u16* __restrict__ xb) {
  const int gsz = gridDim.x * blockDim.x;
  for (int i = blockIdx.x * blockDim.x + threadIdx.x; i < T_ * B_ * 512; i += gsz) {
    int k = i & 511;
    int b = (i >> 9) & 255;
    int t = i >> 17;
    float v = (k < INS) ? x[((size_t)b * T_ + t) * INS + k] : 0.f;
    xb[i] = f2bf(v);
  }
}

__global__ void prep_sigma_kernel(const float* __restrict__ raw,
                                  u16* __restrict__ Gb, u16* __restrict__ Ldb,
                                  float* __restrict__ idio)
{
  const int gsz = gridDim.x * blockDim.x;
  const int g0  = blockIdx.x * blockDim.x + threadIdx.x;
  for (int i = g0; i < 256 * 512 * 32; i += gsz) {
    int b = i >> 14, rr = i & 16383, n = rr >> 5, f = rr & 31;
    const float* rb = raw + (size_t)b * NDP;
    float ld = (n < 500) ? rb[n * 32 + f] : 0.f;
    float fv = __expf(rb[16000 + f]);
    Ldb[i] = f2bf(ld);
    Gb[i]  = f2bf(ld * fv);
  }
  for (int i = g0; i < 256 * 512; i += gsz) {
    int b = i >> 9, a = i & 511;
    if (a < 500) idio[(size_t)b * 500 + a] = __expf(raw[(size_t)b * NDP + 16032 + a]);
  }
}

// ---------------------------------------------------------------- GEMM: C[M][N] = A[M][K] @ Bw[N][K]^T + bias
// global_load_lds width-16 staging: linear LDS dest, inverse-swizzled global
// source, swizzled ds_read (both-sides rule).
template <int OUT_BF16>
__global__ __launch_bounds__(256) void gemm_bt(
    const u16* __restrict__ A, const u16* __restrict__ Bw,
    const float* __restrict__ bias, void* __restrict__ C,
    int M, int N, int K)
{
  __shared__ alignas(16) u16 As[128 * 32];
  __shared__ alignas(16) u16 Bs[128 * 32];
  const int tid = threadIdx.x;
  const int wave = tid >> 6, lane = tid & 63;
  const int m0 = blockIdx.y * 128, n0 = blockIdx.x * 128;
  const int wr = wave >> 1, wc = wave & 1;

  // staging map: 16B slot s in [0,512): content (row = s>>2, ks = (s&3)^(row&3))
  const int sl0 = wave * 64 + lane;
  const int sl1 = 256 + wave * 64 + lane;
  const int r0s = sl0 >> 2, k0s = (sl0 & 3) ^ (r0s & 3);
  const int r1s = sl1 >> 2, k1s = (sl1 & 3) ^ (r1s & 3);
  const u16* srcA0 = A  + (size_t)(m0 + r0s) * K + k0s * 8;
  const u16* srcA1 = A  + (size_t)(m0 + r1s) * K + k1s * 8;
  const u16* srcB0 = Bw + (size_t)(n0 + r0s) * K + k0s * 8;
  const u16* srcB1 = Bw + (size_t)(n0 + r1s) * K + k1s * 8;
  u16* ldsA0 = As + (size_t)(wave * 64) * 8;
  u16* ldsA1 = As + (size_t)(256 + wave * 64) * 8;
  u16* ldsB0 = Bs + (size_t)(wave * 64) * 8;
  u16* ldsB1 = Bs + (size_t)(256 + wave * 64) * 8;

  floatx4 zero = {0.f, 0.f, 0.f, 0.f};
  floatx4 acc[4][4];
#pragma unroll
  for (int i = 0; i < 4; i++)
#pragma unroll
    for (int j = 0; j < 4; j++) acc[i][j] = zero;

  for (int kc = 0; kc < K; kc += 32) {
    __syncthreads();                 // previous tile's reads done
    gload16(srcA0 + kc, ldsA0);
    gload16(srcA1 + kc, ldsA1);
    gload16(srcB0 + kc, ldsB0);
    gload16(srcB1 + kc, ldsB1);
    __syncthreads();                 // vmcnt(0) drain -> LDS-DMA complete

    const int kg = lane >> 4;
    bf16x8 af[4], bfr[4];
#pragma unroll
    for (int i = 0; i < 4; i++) {
      int rowa = wr * 64 + i * 16 + (lane & 15);
      af[i] = *(const bf16x8*)(As + rowa * 32 + ((kg ^ (rowa & 3)) << 3));
      int rowb = wc * 64 + i * 16 + (lane & 15);
      bfr[i] = *(const bf16x8*)(Bs + rowb * 32 + ((kg ^ (rowb & 3)) << 3));
    }
#pragma unroll
    for (int i = 0; i < 4; i++)
#pragma unroll
      for (int j = 0; j < 4; j++)
        acc[i][j] = __builtin_amdgcn_mfma_f32_16x16x32_bf16(af[i], bfr[j], acc[i][j], 0, 0, 0);
  }

  const int r0 = (lane >> 4) * 4, cl = lane & 15;
#pragma unroll
  for (int j = 0; j < 4; j++) {
    int col = n0 + wc * 64 + j * 16 + cl;
    float bv = bias[col];
#pragma unroll
    for (int i = 0; i < 4; i++) {
      int row = m0 + wr * 64 + i * 16 + r0;
#pragma unroll
      for (int r = 0; r < 4; r++) {
        float v = acc[i][j][r] + bv;
        if (OUT_BF16) ((u16*)C)[(size_t)(row + r) * N + col] = f2bf(v);
        else          ((float*)C)[(size_t)(row + r) * N + col] = v;
      }
    }
  }
}

// ---------------------------------------------------------------- Fused 2-layer LSTM, split flag domains
// 256 blocks x 512 threads (1 block/CU, all co-resident). bm=blockIdx>>5 (8 batch
// groups of 32), bn=blockIdx&31 (32 gate slices of 64 rows). 8 waves = 4 row-groups
// x 2 K-halves (kh).  Exchange transport = round-2 flag barrier (single-cacheline
// polls; round-4's data-word polling congested the fabric: 1.08 GB FETCH).
// NEW: two flag domains to overlap the visibility RT with compute:
//   flag0[bn] = t+1 published MID-iteration, right after h0(t) stores drain
//     (stage + 8 L0 MFMAs + L0 elementwise) -- peers' next-iter wait overlaps
//     our remaining L1 work.
//   flag1[bn] = t published at iteration end (h1(t-1)); polled LATE (just before
//     the h1-consuming MFMAs), so its RT hides under the h0-phase.
// L1's K-split: kh=0 waves do w_ih1 x h0(t-1) -> hoisted into the early h0 phase;
// kh=1 waves do w_hh1 x h1(t-2) after the late flag1 poll.
// Overwrite safety (induction as round 2): flag0 >= t  =>  peers' staging reads of
// hp0 slot t&1 (done at their iter t-1, before their flag0=t publish) completed;
// flag1 analogous for hp1 slot (t+1)&1 via peers' iter t-1 staging before flag0=t.
__global__ __launch_bounds__(512, 2) void lstm_fused_kernel(
    const u16* __restrict__ xg,     // [64][256][2048] bf16, permuted gate order
    const u16* __restrict__ whh0,   // [2048][512]  bf16, permuted rows
    const u16* __restrict__ w1,     // [2048][1024] bf16, permuted rows, cols [w_ih1 | w_hh1]
    const float* __restrict__ bias1p,
    u16* __restrict__ hp0,          // [2][256][512] ping-pong h0
    u16* __restrict__ hp1,          // [2][256][512] ping-pong h1
    u16* __restrict__ hfin,         // [256][512] final h1(63)
    unsigned* __restrict__ bars)    // [8][64]: [bm][0..31]=flag0, [bm][32..63]=flag1
{
  const int tid  = threadIdx.x;
  const int wv   = tid >> 6, lane = tid & 63;
  const int rw   = wv >> 1,  kh   = wv & 1;
  const int bl   = lane & 15, qd  = lane >> 4;
  const int bm   = blockIdx.x >> 5;
  const int bn   = blockIdx.x & 31;
  const int bbase = bm << 5;        // 32 batches
  const int pbase = bn << 6;        // 64 gate rows

  __shared__ alignas(16) u16 h_lds[2 * 32 * 512];   // 64 KB: [0]=h0(t-1), [1]=h1(t-2)
  __shared__ alignas(16) float gates0[2 * 32 * 68]; // [kh][batch32][68] partial L0 gates
  __shared__ alignas(16) float gates1[2 * 32 * 68]; // [kh][batch32][68] partial L1 gates

  bf16x8 wf0[8], wf1[16];
  {
    const u16* wp = whh0 + (size_t)(pbase + rw * 16 + bl) * 512 + kh * 256 + qd * 8;
#pragma unroll
    for (int kc = 0; kc < 8; kc++)  wf0[kc] = *(const bf16x8*)(wp + kc * 32);
    const u16* wq = w1 + (size_t)(pbase + rw * 16 + bl) * 1024 + kh * 512 + qd * 8;
#pragma unroll
    for (int kc = 0; kc < 16; kc++) wf1[kc] = *(const bf16x8*)(wq + kc * 32);
  }

  const int eb = tid >> 4, ej = tid & 15;          // elementwise ownership
  const float4 bq = *(const float4*)(bias1p + pbase + ej * 4);
  float c0 = 0.f, c1 = 0.f;
  unsigned* f0 = bars + bm * 64;
  unsigned* f1 = f0 + 32;
  const size_t hoff = (size_t)(bbase + eb) * H_ + (bn << 4) + ej;
  const floatx4 zero = {0.f, 0.f, 0.f, 0.f};

#pragma unroll 1
  for (int t = 0; t <= 64; t++) {
    // ---- S1: wait for peers' h0(t-1)  (flag0 >= t; trivially true at t=0)
    if (t >= 1 && tid < 64) {
      const unsigned tgt = (unsigned)t;
      for (;;) {
        unsigned v = tgt;
        if (lane < 32)
          v = __hip_atomic_load(f0 + lane, __ATOMIC_RELAXED, __HIP_MEMORY_SCOPE_AGENT);
        if (__all(v >= tgt)) break;
        __builtin_amdgcn_s_sleep(1);
      }
    }
    __syncthreads();

    // ---- S2: stage h0(t-1) [hp0 slot (t+1)&1]; prefetch xg(t)
    {
      const u64* s0 = (const u64*)(hp0 + (size_t)((t + 1) & 1) * (B_ * H_));
#pragma unroll
      for (int i = 0; i < 4; i++) {
        int idx = tid + (i << 9);                  // 0..2047: 32 batches x 64 16B-units
        int bb = idx >> 6, u = idx & 63;
        size_t gp = ((size_t)(bbase + bb) * 64 + u) * 2;
        u64 lo = __hip_atomic_load(s0 + gp,     __ATOMIC_RELAXED, __HIP_MEMORY_SCOPE_AGENT);
        u64 hi = __hip_atomic_load(s0 + gp + 1, __ATOMIC_RELAXED, __HIP_MEMORY_SCOPE_AGENT);
        int dst = bb * 512 + ((u ^ (bb & 7)) << 3);
        uint2 l2 = __builtin_bit_cast(uint2, lo), h2 = __builtin_bit_cast(uint2, hi);
        uint4 q = {l2.x, l2.y, h2.x, h2.y};
        *(uint4*)(h_lds + dst) = q;
      }
    }
    ushort4 xr = {0, 0, 0, 0};
    if (t < 64)
      xr = *(const ushort4*)(xg + ((size_t)t * B_ + bbase + eb) * G_ + pbase + ej * 4);
    __syncthreads();

    // ---- h0 phase MFMAs: L0 (all waves, K-half) + L1's w_ih1 part (kh=0 waves)
    floatx4 acc0[2] = {zero, zero};
    floatx4 acc1[2] = {zero, zero};
    if (t < 64) {
#pragma unroll
      for (int kc = 0; kc < 8; kc++) {
        int kg = kh * 32 + kc * 4 + qd;
        int sw = (kg ^ (bl & 7)) << 3;
        bf16x8 a0 = *(const bf16x8*)(h_lds + bl * 512 + sw);
        bf16x8 a1 = *(const bf16x8*)(h_lds + (16 + bl) * 512 + sw);
        acc0[0] = __builtin_amdgcn_mfma_f32_16x16x32_bf16(a0, wf0[kc], acc0[0], 0, 0, 0);
        acc0[1] = __builtin_amdgcn_mfma_f32_16x16x32_bf16(a1, wf0[kc], acc0[1], 0, 0, 0);
      }
    }
    if (kh == 0) {                                 // w_ih1 x h0(t-1)
#pragma unroll
      for (int kc = 0; kc < 16; kc++) {
        int kg = kc * 4 + qd;
        int sw = (kg ^ (bl & 7)) << 3;
        bf16x8 a0 = *(const bf16x8*)(h_lds + bl * 512 + sw);
        bf16x8 a1 = *(const bf16x8*)(h_lds + (16 + bl) * 512 + sw);
        acc1[0] = __builtin_amdgcn_mfma_f32_16x16x32_bf16(a0, wf1[kc], acc1[0], 0, 0, 0);
        acc1[1] = __builtin_amdgcn_mfma_f32_16x16x32_bf16(a1, wf1[kc], acc1[1], 0, 0, 0);
      }
    }

    // ---- S3: L0 partial gates -> LDS
    {
      const int rowc = rw * 16 + bl;
#pragma unroll
      for (int bt = 0; bt < 2; bt++)
#pragma unroll
        for (int r = 0; r < 4; r++) {
          int bat = bt * 16 + qd * 4 + r;
          gates0[(kh * 32 + bat) * 68 + rowc] = acc0[bt][r];
        }
    }
    __syncthreads();

    // ---- L0 elementwise + h0(t) store
    if (t < 64) {
      float4 ga = *(const float4*)(gates0 + (0 * 32 + eb) * 68 + ej * 4);
      float4 gc = *(const float4*)(gates0 + (1 * 32 + eb) * 68 + ej * 4);
      float gi = ga.x + gc.x + bf2f(xr.x);
      float gf = ga.y + gc.y + bf2f(xr.y);
      float gg = ga.z + gc.z + bf2f(xr.z);
      float go = ga.w + gc.w + bf2f(xr.w);
      c0 = sigm(gf) * c0 + sigm(gi) * tanh_(gg);
      float h = sigm(go) * tanh_(c0);
      __hip_atomic_store(hp0 + (size_t)(t & 1) * (B_ * H_) + hoff, f2bf(h),
                         __ATOMIC_RELAXED, __HIP_MEMORY_SCOPE_AGENT);
    }

    // ---- S4: drain h0 stores, publish flag0 EARLY; late poll of flag1
    __syncthreads();                               // vmcnt(0): h0 stores ack'd
    if (t < 64 && tid == 0)
      __hip_atomic_store(f0 + bn, (unsigned)(t + 1),
                         __ATOMIC_RELAXED, __HIP_MEMORY_SCOPE_AGENT);
    if (t >= 1 && tid < 64) {                      // need h1(t-2): flag1 >= t-1
      const unsigned tgt = (unsigned)(t - 1);
      for (;;) {
        unsigned v = tgt;
        if (lane < 32)
          v = __hip_atomic_load(f1 + lane, __ATOMIC_RELAXED, __HIP_MEMORY_SCOPE_AGENT);
        if (__all(v >= tgt)) break;
        __builtin_amdgcn_s_sleep(1);
      }
    }
    __syncthreads();                               // S5: flag1 confirmed for all

    // ---- S6: stage h1(t-2) [hp1 slot t&1]
    {
      const u64* s1 = (const u64*)(hp1 + (size_t)(t & 1) * (B_ * H_));
#pragma unroll
      for (int i = 0; i < 4; i++) {
        int idx = tid + (i << 9);
        int bb = idx >> 6, u = idx & 63;
        size_t gp = ((size_t)(bbase + bb) * 64 + u) * 2;
        u64 lo = __hip_atomic_load(s1 + gp,     __ATOMIC_RELAXED, __HIP_MEMORY_SCOPE_AGENT);
        u64 hi = __hip_atomic_load(s1 + gp + 1, __ATOMIC_RELAXED, __HIP_MEMORY_SCOPE_AGENT);
        int dst = 16384 + bb * 512 + ((u ^ (bb & 7)) << 3);
        uint2 l2 = __builtin_bit_cast(uint2, lo), h2 = __builtin_bit_cast(uint2, hi);
        uint4 q = {l2.x, l2.y, h2.x, h2.y};
        *(uint4*)(h_lds + dst) = q;
      }
    }
    __syncthreads();

    // ---- h1 phase MFMAs: L1's w_hh1 part (kh=1 waves)
    if (kh == 1) {
#pragma unroll
      for (int kc = 0; kc < 16; kc++) {
        int kg = kc * 4 + qd;
        int sw = (kg ^ (bl & 7)) << 3;
        bf16x8 a0 = *(const bf16x8*)(h_lds + 16384 + bl * 512 + sw);
        bf16x8 a1 = *(const bf16x8*)(h_lds + 16384 + (16 + bl) * 512 + sw);
        acc1[0] = __builtin_amdgcn_mfma_f32_16x16x32_bf16(a0, wf1[kc], acc1[0], 0, 0, 0);
        acc1[1] = __builtin_amdgcn_mfma_f32_16x16x32_bf16(a1, wf1[kc], acc1[1], 0, 0, 0);
      }
    }

    // ---- S7: L1 partial gates -> LDS
    {
      const int rowc = rw * 16 + bl;
#pragma unroll
      for (int bt = 0; bt < 2; bt++)
#pragma unroll
        for (int r = 0; r < 4; r++) {
          int bat = bt * 16 + qd * 4 + r;
          gates1[(kh * 32 + bat) * 68 + rowc] = acc1[bt][r];
        }
    }
    __syncthreads();

    // ---- L1 elementwise + h1(t-1) store
    if (t >= 1) {
      float4 ga = *(const float4*)(gates1 + (0 * 32 + eb) * 68 + ej * 4);
      float4 gc = *(const float4*)(gates1 + (1 * 32 + eb) * 68 + ej * 4);
      float gi = ga.x + gc.x + bq.x;
      float gf = ga.y + gc.y + bq.y;
      float gg = ga.z + gc.z + bq.z;
      float go = ga.w + gc.w + bq.w;
      c1 = sigm(gf) * c1 + sigm(gi) * tanh_(gg);
      float h = sigm(go) * tanh_(c1);
      u16 hb = f2bf(h);
      if (t < 64)
        __hip_atomic_store(hp1 + (size_t)((t + 1) & 1) * (B_ * H_) + hoff, hb,
                           __ATOMIC_RELAXED, __HIP_MEMORY_SCOPE_AGENT);
      else
        hfin[hoff] = hb;                           // kernel-boundary coherent
    }

    // ---- S8: drain h1 stores, publish flag1
    if (t >= 1 && t < 64) {
      __syncthreads();                             // vmcnt(0): h1 stores ack'd
      if (tid == 0)
        __hip_atomic_store(f1 + bn, (unsigned)t,
                           __ATOMIC_RELAXED, __HIP_MEMORY_SCOPE_AGENT);
    }
  }
}

// ---------------------------------------------------------------- Sigma: out[b] = G_b @ Ld_b^T + diag(idio)
__global__ __launch_bounds__(256) void sigma_kernel(
    const u16* __restrict__ Gb, const u16* __restrict__ Ldb,
    const float* __restrict__ idio, float* __restrict__ out)
{
  const int bz = blockIdx.z;
  const int n0 = blockIdx.y * 128;
  const int m0 = blockIdx.x * 128;
  __shared__ alignas(16) u16 As[128 * 32];
  __shared__ alignas(16) u16 Bs[128 * 32];
  const int tid = threadIdx.x, wave = tid >> 6, lane = tid & 63;
  const int wr = wave >> 1, wc = wave & 1;

  const u16* ga = Gb  + (size_t)bz * (512 * 32) + n0 * 32;
  const u16* gb = Ldb + (size_t)bz * (512 * 32) + m0 * 32;
#pragma unroll
  for (int i = 0; i < 2; i++) {
    int idx = tid + (i << 8);
    int row = idx >> 2, ks = idx & 3;
    int off = row * 32 + ((ks ^ (row & 3)) << 3);
    *(uint4*)(As + off) = *(const uint4*)(ga + idx * 8);
    *(uint4*)(Bs + off) = *(const uint4*)(gb + idx * 8);
  }
  __syncthreads();

  const int kg = lane >> 4;
  bf16x8 af[4], bfr[4];
#pragma unroll
  for (int i = 0; i < 4; i++) {
    int rowa = wr * 64 + i * 16 + (lane & 15);
    af[i] = *(const bf16x8*)(As + rowa * 32 + ((kg ^ (rowa & 3)) << 3));
    int rowb = wc * 64 + i * 16 + (lane & 15);
    bfr[i] = *(const bf16x8*)(Bs + rowb * 32 + ((kg ^ (rowb & 3)) << 3));
  }
  floatx4 zero = {0.f, 0.f, 0.f, 0.f};
  floatx4 acc[4][4];
#pragma unroll
  for (int i = 0; i < 4; i++)
#pragma unroll
    for (int j = 0; j < 4; j++)
      acc[i][j] = __builtin_amdgcn_mfma_f32_16x16x32_bf16(af[i], bfr[j], zero, 0, 0, 0);

  const int r0 = (lane >> 4) * 4, cl = lane & 15;
  float* ob = out + (size_t)bz * 250000;
#pragma unroll
  for (int j = 0; j < 4; j++) {
    int col = m0 + wc * 64 + j * 16 + cl;
#pragma unroll
    for (int i = 0; i < 4; i++) {
      int row = n0 + wr * 64 + i * 16 + r0;
#pragma unroll
      for (int r = 0; r < 4; r++) {
        int rr = row + r;
        if (rr < 500 && col < 500) {
          float v = acc[i][j][r];
          if (rr == col) v += idio[(size_t)bz * 500 + rr];
          ob[(size_t)rr * 500 + col] = v;
        }
      }
    }
  }
}

// ---------------------------------------------------------------- launcher
extern "C" void kernel_launch(void* const* d_in, const int* in_sizes, int n_in,
                              void* d_out, int out_size, void* d_ws, size_t ws_size,
                              hipStream_t stream)
{
  const float* x     = (const float*)d_in[0];
  const float* w_ih0 = (const float*)d_in[1];
  const float* w_hh0 = (const float*)d_in[2];
  const float* b_ih0 = (const float*)d_in[3];
  const float* b_hh0 = (const float*)d_in[4];
  const float* w_ih1 = (const float*)d_in[5];
  const float* w_hh1 = (const float*)d_in[6];
  const float* b_ih1 = (const float*)d_in[7];
  const float* b_hh1 = (const float*)d_in[8];
  const float* fc_w  = (const float*)d_in[9];
  const float* fc_b  = (const float*)d_in[10];
  float* out = (float*)d_out;

  char* p = (char*)d_ws;
  auto alloc = [&](size_t n) { char* r = p; p += (n + 255) & ~(size_t)255; return r; };

  u16*  xb     = (u16*)alloc((size_t)T_ * B_ * 512 * 2);
  u16*  wih0b  = (u16*)alloc((size_t)2048 * 512 * 2);
  u16*  whh0b  = (u16*)alloc((size_t)2048 * 512 * 2);
  u16*  w1b    = (u16*)alloc((size_t)2048 * 1024 * 2);
  u16*  fcwb   = (u16*)alloc((size_t)NDP * 512 * 2);
  float* bias0p = (float*)alloc(2048 * 4);
  float* bias1p = (float*)alloc(2048 * 4);
  float* fcbp   = (float*)alloc((size_t)NDP * 4);
  u16*  xg0    = (u16*)alloc((size_t)T_ * B_ * G_ * 2);
  u16*  hp0    = (u16*)alloc((size_t)2 * B_ * H_ * 2);
  u16*  hp1    = (u16*)alloc((size_t)2 * B_ * H_ * 2);
  u16*  hfin   = (u16*)alloc((size_t)B_ * H_ * 2);
  float* raw    = (float*)alloc((size_t)B_ * NDP * 4);
  u16*  Gbuf   = (u16*)alloc((size_t)256 * 512 * 32 * 2);
  u16*  Ldbuf  = (u16*)alloc((size_t)256 * 512 * 32 * 2);
  float* idio   = (float*)alloc((size_t)256 * 512 * 4);
  unsigned* bars0 = (unsigned*)alloc(8 * 64 * 4);

  hipMemsetAsync(hp0, 0, (size_t)2 * B_ * H_ * 2, stream);
  hipMemsetAsync(hp1, 0, (size_t)2 * B_ * H_ * 2, stream);
  hipMemsetAsync(bars0, 0, 8 * 64 * 4, stream);

  dim3 blk(256);
  prep_weights_kernel<<<512, blk, 0, stream>>>(w_ih0, w_hh0, b_ih0, b_hh0,
                                               w_ih1, w_hh1, b_ih1, b_hh1,
                                               fc_w, fc_b,
                                               wih0b, whh0b, w1b, fcwb,
                                               bias0p, bias1p, fcbp);
  prep_x_kernel<<<1024, blk, 0, stream>>>(x, xb);

  // xg0 = xb @ wih0b^T + (b_ih0 + b_hh0)   [16384 x 2048 x 512]
  gemm_bt<1><<<dim3(G_ / 128, (T_ * B_) / 128), blk, 0, stream>>>(
      xb, wih0b, bias0p, xg0, T_ * B_, G_, 512);

  // fused two-layer LSTM; final h1(63) lands in hfin
  lstm_fused_kernel<<<256, dim3(512), 0, stream>>>(
      xg0, whh0b, w1b, bias1p, hp0, hp1, hfin, bars0);

  // raw = h1_final @ fcwb^T + fc_b  [256 x 16640 x 512]
  gemm_bt<0><<<dim3(NDP / 128, B_ / 128), blk, 0, stream>>>(
      hfin, fcwb, fcbp, raw, B_, NDP, 512);

  prep_sigma_kernel<<<1024, blk, 0, stream>>>(raw, Gbuf, Ldbuf, idio);
  sigma_kernel<<<dim3(4, 4, 256), blk, 0, stream>>>(Gbuf, Ldbuf, idio, out);
}